// Round 7
// baseline (271.313 us; speedup 1.0000x reference)
//
#include <hip/hip_runtime.h>
#include <hip/hip_bf16.h>

// GroupConv2D: NHWC, B=32, H=W=56, Cin=Cout=256, groups=8 (32 ch/group), 3x3 SAME.
// Implicit-GEMM per group: 16x16 tiles, K=288 (9 taps x 32 ci), mfma_f32_16x16x32_bf16.
//
// R9: fp32-DIRECT conv (no LDS, no barriers, NO image prep).
// R8 diagnosis (90.6us, FETCH 222MB on a 55MB image): bf16 group slice = 64B =
// HALF a cache line; the other half belongs to a different group's block on a
// different XCD -> ~2x line fetch + scattered-64B streams at 58% HBM efficiency.
// The ORIGINAL fp32 layout gives a group slice = 32ch x 4B = exactly ONE full
// 128B line. So read fp32 directly, convert to bf16 in-register at consume time
// (36 independent load->cvt->MFMA chains; the R1-R5 wall was LDS-staging
// serialization, not conversion). Kills iprep (~28us) + big-ws entirely.
//  - tiles-outer / taps-inner: per-tile working set ~7KB -> L1-resident tap reuse.
//  - OOB taps: branchless address-select to a 128B zero pad in ws.
//  - XCD-chunked swizzle: rt-adjacent blocks (2-row halo overlap) share an L2.
// Predict: gconv 45-65us, FETCH 120-170MB, WRITE ~100MB (spill check), VGPR<=110,
// LDS 0, Occ ~50%. dur ~182-195. If ~90us despite full lines -> issue-bound, ablate.

#define R_ 4                 // output rows per block-strip

typedef __bf16 bf16x8 __attribute__((ext_vector_type(8)));
typedef float floatx4 __attribute__((ext_vector_type(4)));
typedef unsigned short ushortx4 __attribute__((ext_vector_type(4)));

#define WGT_USHORTS 73728u      // 8*9*32*32
#define ZPAD_USHORTS 64u        // 128B zero pad (OOB load target)

__device__ __forceinline__ unsigned short f2bf(float f) {
    unsigned int u = __builtin_bit_cast(unsigned int, f);
    u += 0x7fffu + ((u >> 16) & 1u);           // round-to-nearest-even
    return (unsigned short)(u >> 16);
}

__device__ __forceinline__ bf16x8 cvt_frag(float4 lo, float4 hi) {
    union { bf16x8 v; __hip_bfloat162 h[4]; } u;
    u.h[0] = __float22bfloat162_rn(make_float2(lo.x, lo.y));
    u.h[1] = __float22bfloat162_rn(make_float2(lo.z, lo.w));
    u.h[2] = __float22bfloat162_rn(make_float2(hi.x, hi.y));
    u.h[3] = __float22bfloat162_rn(make_float2(hi.z, hi.w));
    return u.v;
}

// ---- wprep: wgt fp32 [tap][ci][co256] -> bf16 [g][tap][co][ci]; + 128B zero pad
__global__ __launch_bounds__(256)
void wprep(const float* __restrict__ wgt, unsigned short* __restrict__ wbf) {
    const int i = blockIdx.x * 256 + threadIdx.x;       // grid sized exactly (288 blocks)
    if (blockIdx.x == 0 && threadIdx.x < ZPAD_USHORTS)
        wbf[WGT_USHORTS + threadIdx.x] = 0;
    const int co256 = i & 255;
    const int tmp   = i >> 8;
    const int ci    = tmp & 31;
    const int kk    = tmp >> 5;                          // 0..8
    const int g  = co256 >> 5;
    const int co = co256 & 31;
    wbf[((g * 9 + kk) * 32 + co) * 32 + ci] = f2bf(wgt[i]);
}

// ---- main kernel: direct conv from fp32 input; no LDS, no barriers ----
__global__ __launch_bounds__(256, 4)
void gconv_f32d(const float* __restrict__ in, const unsigned short* __restrict__ wbf,
                const float* __restrict__ bias, float* __restrict__ out) {
    // XCD-chunked swizzle: 3584 blocks, 8 XCDs, 448/XCD; hardware round-robins
    // blockIdx%8 -> give each XCD a CONTIGUOUS logical range so rt-neighbors
    // (which share 2 halo rows) hit the same L2. 3584%8==0 -> bijective.
    const int h = blockIdx.x;
    const int L = (h & 7) * 448 + (h >> 3);
    const int rt = L % 14;                 // row-strip, fastest -> L2-local halo
    const int r2 = L / 14;
    const int g  = r2 & 7;                 // group
    const int b  = r2 >> 3;                // batch
    const int y0 = rt * R_;

    const int tid  = threadIdx.x;
    const int wv   = tid >> 6;
    const int lane = tid & 63;
    const int lc   = lane & 15;    // weights-A: m (co); pixels-B: n (pixel)
    const int quad = lane >> 4;

    // 14 pixel tiles (224 px / 16); waves 0,1: 4 tiles; waves 2,3: 3 tiles
    const int nt = (wv < 2) ? 4 : 3;
    const int t0 = (wv < 2) ? (wv * 4) : (8 + (wv - 2) * 3);

    const float* zsrc = (const float*)(wbf + WGT_USHORTS);   // 128B of zeros

    // per-tile center pointer (output pixel) + border flags; group slice is one
    // full 128B line in fp32 NHWC: ch [g*32, g*32+32), lane takes quad*8..+7.
    const float* cptr[4];
    bool rlo[4], rhi[4], clo[4], chi[4];
#pragma unroll
    for (int t = 0; t < 4; ++t) {
        const int tt = (t < nt) ? (t0 + t) : 0;
        const int p  = tt * 16 + lc;           // output pixel 0..223 in strip
        const int yl = p / 56;
        const int xl = p - yl * 56;
        const int yy = y0 + yl;
        cptr[t] = &in[(((b * 56 + yy) * 56 + xl) << 8) + (g << 5) + (quad << 3)];
        rlo[t] = (yy > 0);  rhi[t] = (yy < 55);
        clo[t] = (xl > 0);  chi[t] = (xl < 55);
    }

    // weight fragment base: [g][kk][co][ci] bf16; lane (lc,quad) -> co=lc, ci=quad*8
    const unsigned short* wq = &wbf[(g * 9 * 32) * 32 + (quad << 3)];

    floatx4 acc[4][2];
#pragma unroll
    for (int t = 0; t < 4; ++t) { acc[t][0] = (floatx4)(0.f); acc[t][1] = (floatx4)(0.f); }

    // tiles outer, taps inner: per-tile tap working set ~7KB (L1-friendly);
    // 9 taps x (2 img loads + 2 wgt loads) per tile = deep independent MLP.
#pragma unroll
    for (int t = 0; t < 4; ++t) {
        if (t < nt) {   // wave-uniform
#pragma unroll
            for (int kk = 0; kk < 9; ++kk) {
                const int dy = kk / 3 - 1, dx = kk % 3 - 1;          // compile-time
                const int koff = (dy * 56 + dx) << 8;                // fp32 elems
                const bool oky = (dy == 0) ? true : (dy < 0 ? rlo[t] : rhi[t]);
                const bool okx = (dx == 0) ? true : (dx < 0 ? clo[t] : chi[t]);
                const float* s = (oky && okx) ? (cptr[t] + koff) : zsrc;
                const float4 lo = *reinterpret_cast<const float4*>(s);
                const float4 hi = *reinterpret_cast<const float4*>(s + 4);
                const bf16x8 wb0 = *reinterpret_cast<const bf16x8*>(&wq[(kk * 32 + lc) * 32]);
                const bf16x8 wb1 = *reinterpret_cast<const bf16x8*>(&wq[(kk * 32 + 16 + lc) * 32]);
                const bf16x8 a = cvt_frag(lo, hi);
                // A=weights (m=co), B=pixels (n=pixel) -> D[row=co][col=pixel]
                acc[t][0] = __builtin_amdgcn_mfma_f32_16x16x32_bf16(wb0, a, acc[t][0], 0, 0, 0);
                acc[t][1] = __builtin_amdgcn_mfma_f32_16x16x32_bf16(wb1, a, acc[t][1], 0, 0, 0);
            }
        }
    }

    // ---- epilogue: D row=quad*4+r (co), col=lc (pixel); two dwordx4 per tile.
    // Lanes lc,lc+16,lc+32,lc+48 cover co 0..15 of one pixel -> contiguous 64B.
    const float4 bv0 = *reinterpret_cast<const float4*>(&bias[(g << 5) + (quad << 2)]);
    const float4 bv1 = *reinterpret_cast<const float4*>(&bias[(g << 5) + 16 + (quad << 2)]);
    const int obase = (((b * 56 + y0) * 56) << 8) + (g << 5) + (quad << 2);
#pragma unroll
    for (int t = 0; t < 4; ++t) {
        if (t < nt) {
            const int p = (t0 + t) * 16 + lc;
            const int y = p / 56;
            const int x = p - y * 56;
            float* o = &out[obase + ((y * 56 + x) << 8)];
            float4 s0, s1;
            s0.x = acc[t][0][0] + bv0.x; s0.y = acc[t][0][1] + bv0.y;
            s0.z = acc[t][0][2] + bv0.z; s0.w = acc[t][0][3] + bv0.w;
            s1.x = acc[t][1][0] + bv1.x; s1.y = acc[t][1][1] + bv1.y;
            s1.z = acc[t][1][2] + bv1.z; s1.w = acc[t][1][3] + bv1.w;
            *reinterpret_cast<float4*>(o)      = s0;
            *reinterpret_cast<float4*>(o + 16) = s1;
        }
    }
}

// ---- last-resort fallback (round-1 kernel, no workspace) ----
__global__ __launch_bounds__(256, 2)
void gconv_mfma_ldsw(const float* __restrict__ in, const float* __restrict__ wgt,
                     const float* __restrict__ bias, float* __restrict__ out) {
    const int rt = blockIdx.x, g = blockIdx.y, b = blockIdx.z;
    const int y0 = rt * 8;
    __shared__ unsigned short lds_in[10 * 58 * 32];
    __shared__ unsigned short lds_w[9 * 32 * 32];
    const int tid = threadIdx.x;
    for (int i = tid; i < 9 * 32 * 32; i += 256) {
        const int co = i & 31, ci = (i >> 5) & 31, kk = i >> 10;
        lds_w[(kk * 32 + co) * 32 + ci] = f2bf(wgt[(kk * 32 + ci) * 256 + g * 32 + co]);
    }
    for (int c = tid; c < 10 * 58 * 8; c += 256) {
        const int row = c / 464, rem = c - row * 464, col = rem >> 3, q = rem & 7;
        const int gy = y0 - 1 + row, gx = col - 1;
        float4 v = make_float4(0.f, 0.f, 0.f, 0.f);
        if ((unsigned)gy < 56u && (unsigned)gx < 56u)
            v = *reinterpret_cast<const float4*>(&in[(((b * 56 + gy) * 56 + gx) * 256) + g * 32 + q * 4]);
        ushortx4 p;
        p.x = f2bf(v.x); p.y = f2bf(v.y); p.z = f2bf(v.z); p.w = f2bf(v.w);
        *reinterpret_cast<ushortx4*>(&lds_in[(row * 58 + col) * 32 + q * 4]) = p;
    }
    __syncthreads();
    const int wv = tid >> 6, lane = tid & 63, lc = lane & 15, quad = lane >> 4;
    int lane_base[7];
#pragma unroll
    for (int t = 0; t < 7; ++t) {
        const int p = (wv * 7 + t) * 16 + lc;
        const int yl = p / 56, xl = p - yl * 56;
        lane_base[t] = (yl * 58 + xl) * 32 + quad * 8;
    }
    floatx4 acc[7][2];
#pragma unroll
    for (int t = 0; t < 7; ++t) { acc[t][0] = (floatx4)(0.f); acc[t][1] = (floatx4)(0.f); }
#pragma unroll
    for (int kk = 0; kk < 9; ++kk) {
        const int ky = kk / 3, kx = kk % 3;
        const int koff = (ky * 58 + kx) * 32;
        const bf16x8 bf0 = *reinterpret_cast<const bf16x8*>(&lds_w[(kk * 32 + lc) * 32 + quad * 8]);
        const bf16x8 bf1 = *reinterpret_cast<const bf16x8*>(&lds_w[(kk * 32 + 16 + lc) * 32 + quad * 8]);
#pragma unroll
        for (int t = 0; t < 7; ++t) {
            const bf16x8 a = *reinterpret_cast<const bf16x8*>(&lds_in[lane_base[t] + koff]);
            acc[t][0] = __builtin_amdgcn_mfma_f32_16x16x32_bf16(a, bf0, acc[t][0], 0, 0, 0);
            acc[t][1] = __builtin_amdgcn_mfma_f32_16x16x32_bf16(a, bf1, acc[t][1], 0, 0, 0);
        }
    }
    const float bv0 = bias[g * 32 + lc], bv1 = bias[g * 32 + 16 + lc];
#pragma unroll
    for (int t = 0; t < 7; ++t)
#pragma unroll
        for (int r = 0; r < 4; ++r) {
            const int p = (wv * 7 + t) * 16 + quad * 4 + r;
            const int y = p / 56, x = p - y * 56;
            float* o = &out[(((b * 56) + y0 + y) * 56 + x) * 256 + g * 32];
            o[lc] = acc[t][0][r] + bv0;
            o[16 + lc] = acc[t][1][r] + bv1;
        }
}

extern "C" void kernel_launch(void* const* d_in, const int* in_sizes, int n_in,
                              void* d_out, int out_size, void* d_ws, size_t ws_size,
                              hipStream_t stream) {
    const float* in   = (const float*)d_in[0];
    const float* wgt  = (const float*)d_in[1];
    const float* bias = (const float*)d_in[2];
    float* out        = (float*)d_out;

    const size_t need_wgt = (size_t)(WGT_USHORTS + ZPAD_USHORTS) * 2;   // ~147.6 KB

    if (d_ws != nullptr && ws_size >= need_wgt) {
        unsigned short* wbf = (unsigned short*)d_ws;
        wprep<<<dim3(288, 1, 1), dim3(256, 1, 1), 0, stream>>>(wgt, wbf);
        gconv_f32d<<<dim3(3584, 1, 1), dim3(256, 1, 1), 0, stream>>>(in, wbf, bias, out);
    } else {
        gconv_mfma_ldsw<<<dim3(7, 8, 32), dim3(256, 1, 1), 0, stream>>>(in, wgt, bias, out);
    }
}